// Round 6
// baseline (207.256 us; speedup 1.0000x reference)
//
#include <hip/hip_runtime.h>
#include <hip/hip_bf16.h>

#define HIDDEN 512
#define M_PER_TOKEN 32
#define BUCKET_CAP 32   // Poisson(5.24) users/row; P(>32) ~ 1e-11 for 50k rows
#define RPW 8           // rows per persistent wave (cross-row pipeline depth)

typedef _Float16 half8 __attribute__((ext_vector_type(8)));
typedef float    f32x4 __attribute__((ext_vector_type(4)));

// ---------------------------------------------------------------------------
// K1: input fp32 -> fp16 (8.4 MB gathered-side table) + zero counts + zero
// ALL 32 bucket slots (so row_ffn can read users[u+q] for any group with a
// benign pid=0 result; removes clamp logic from the gather critical path).
// ---------------------------------------------------------------------------
__global__ __launch_bounds__(256) void prep_kernel(
    const float* __restrict__ input,   // [8192*512]
    _Float16*    __restrict__ in_h,    // [8192*512]
    int*         __restrict__ counts,  // [n_rows]
    int*         __restrict__ padded,  // [n_rows*32]
    int n_chunks, int n_rows)
{
    int i = blockIdx.x * 256 + threadIdx.x;
    if (i < n_chunks) {
        const float4 a = ((const float4*)input)[2 * i];
        const float4 b = ((const float4*)input)[2 * i + 1];
        half8 h;
        h[0] = (_Float16)a.x; h[1] = (_Float16)a.y;
        h[2] = (_Float16)a.z; h[3] = (_Float16)a.w;
        h[4] = (_Float16)b.x; h[5] = (_Float16)b.y;
        h[6] = (_Float16)b.z; h[7] = (_Float16)b.w;
        ((half8*)in_h)[i] = h;
    }
    if (i < n_rows) counts[i] = 0;
    if (i < n_rows * 8) ((int4*)padded)[i] = make_int4(0, 0, 0, 0);
}

// ---------------------------------------------------------------------------
// K2: inverted index. 4 pairs per thread (int4 mask load); bucket slot via
// atomicAdd.
// ---------------------------------------------------------------------------
__global__ __launch_bounds__(256) void scatter_kernel(
    const int* __restrict__ mask,     // [262144]
    int*       __restrict__ counts,   // [n_rows]
    int*       __restrict__ padded,   // [n_rows*32]
    int n_pairs)
{
    int t    = blockIdx.x * 256 + threadIdx.x;
    int base = t * 4;
    if (base + 3 < n_pairs) {
        const int4 m = *(const int4*)(mask + base);
        int r, slot;
        r = m.x; slot = atomicAdd(&counts[r], 1);
        if (slot < BUCKET_CAP) padded[(r << 5) + slot] = base;
        r = m.y; slot = atomicAdd(&counts[r], 1);
        if (slot < BUCKET_CAP) padded[(r << 5) + slot] = base + 1;
        r = m.z; slot = atomicAdd(&counts[r], 1);
        if (slot < BUCKET_CAP) padded[(r << 5) + slot] = base + 2;
        r = m.w; slot = atomicAdd(&counts[r], 1);
        if (slot < BUCKET_CAP) padded[(r << 5) + slot] = base + 3;
    } else {
        for (int i = base; i < n_pairs; ++i) {
            int r = mask[i];
            int slot = atomicAdd(&counts[r], 1);
            if (slot < BUCKET_CAP) padded[(r << 5) + slot] = i;
        }
    }
}

// ---------------------------------------------------------------------------
// 16-lane sum via DPP butterfly (verified in rounds 4/5): quad_perm XOR1,
// XOR2, row_half_mirror, row_mirror -> all 16 sublanes end with the total.
// ---------------------------------------------------------------------------
template <int CTRL>
__device__ __forceinline__ float dpp_add(float v) {
    return v + __int_as_float(__builtin_amdgcn_update_dpp(
        0, __float_as_int(v), CTRL, 0xF, 0xF, true));
}

__device__ __forceinline__ float red16(float v) {
    v = dpp_add<0xB1>(v);   // quad_perm [1,0,3,2]  : i ^ 1
    v = dpp_add<0x4E>(v);   // quad_perm [2,3,0,1]  : i ^ 2
    v = dpp_add<0x141>(v);  // row_half_mirror      : i <-> 7-i within 8
    v = dpp_add<0x140>(v);  // row_mirror           : i <-> 15-i within 16
    return v;
}

__device__ __forceinline__ float dot128(const half8 h, const f32x4 wa,
                                        const f32x4 wb) {
    return (float)h[0]*wa[0] + (float)h[1]*wa[1]
         + (float)h[2]*wa[2] + (float)h[3]*wa[3]
         + (float)h[4]*wb[0] + (float)h[5]*wb[1]
         + (float)h[6]*wb[2] + (float)h[7]*wb[3];
}

// Per-row pipeline state: count, first pid for this quarter, bias, and the
// lane's 32 weight elements (8 x f32x4, explicit members -> never scratch).
struct RState {
    int   c;
    int   pid0;
    float bv;
    f32x4 w0, w1, w2, w3, w4, w5, w6, w7;
};

__device__ __forceinline__ RState issue_state(
    const float* __restrict__ weight, const float* __restrict__ bias,
    const int* __restrict__ counts, const int* __restrict__ padded,
    int r, int s, int q)
{
    RState S;
    S.c    = counts[r];
    S.pid0 = (padded + ((size_t)r << 5))[q];
    S.bv   = bias[r];
    const float* wb = weight + (size_t)r * HIDDEN + s * 8;
    S.w0 = __builtin_nontemporal_load((const f32x4*)(wb +   0));
    S.w1 = __builtin_nontemporal_load((const f32x4*)(wb +   4));
    S.w2 = __builtin_nontemporal_load((const f32x4*)(wb + 128));
    S.w3 = __builtin_nontemporal_load((const f32x4*)(wb + 132));
    S.w4 = __builtin_nontemporal_load((const f32x4*)(wb + 256));
    S.w5 = __builtin_nontemporal_load((const f32x4*)(wb + 260));
    S.w6 = __builtin_nontemporal_load((const f32x4*)(wb + 384));
    S.w7 = __builtin_nontemporal_load((const f32x4*)(wb + 388));
    return S;
}

// ---------------------------------------------------------------------------
// K3 v9: persistent waves, cross-ROW software pipeline.
//  - v8 post-mortem: avg c=5.24 -> 1.3 groups/row; the group pipeline had
//    nothing to overlap. The dominant serial cost was the per-row PROLOGUE
//    (counts->users->weight->gathers), paid by 50016 short-lived waves.
//  - v9: 6250 waves x 8 contiguous rows each. While computing row r, issue
//    row r+1's full state AND its group-0 gathers. Prologue paid once per
//    8 rows; weight stream sequential per wave.
// ---------------------------------------------------------------------------
__global__ __launch_bounds__(256) void row_ffn_kernel(
    const _Float16* __restrict__ in_h,    // [8192, 512] fp16
    const float*    __restrict__ weight,  // [n_rows, 512] fp32
    const float*    __restrict__ bias,    // [n_rows]
    const int*      __restrict__ counts,  // [n_rows]
    const int*      __restrict__ padded,  // [n_rows, 32]
    float*          __restrict__ out,     // [8192, 32]
    int n_rows, int blocks_per_xcd)
{
    const int b    = (int)blockIdx.x;
    const int bsw  = (b & 7) * blocks_per_xcd + (b >> 3);  // XCD-contiguous
    const int wave = threadIdx.x >> 6;
    const int lane = threadIdx.x & 63;
    const int s    = lane & 15;   // sublane within quarter
    const int q    = lane >> 4;   // quarter = which user of the group
    const int wgid = bsw * 4 + wave;

    int r = wgid * RPW;
    if (r >= n_rows) return;
    const int r_end = (r + RPW < n_rows) ? r + RPW : n_rows;

    // prologue: state + group-0 gathers for the first row
    RState S = issue_state(weight, bias, counts, padded, r, s, q);
    const _Float16* ir0 = in_h + (size_t)(S.pid0 >> 5) * HIDDEN + s * 8;
    half8 hl0 = *(const half8*)(ir0);
    half8 hl1 = *(const half8*)(ir0 + 128);
    half8 hl2 = *(const half8*)(ir0 + 256);
    half8 hl3 = *(const half8*)(ir0 + 384);

#pragma unroll
    for (int k = 0; k < RPW; ++k) {
        const int rn = (r + 1 < r_end) ? r + 1 : r;  // clamped prefetch row

        // issue next row's state NOW (waits land next iteration)
        RState SN = issue_state(weight, bias, counts, padded, rn, s, q);

        const int  c     = (S.c > BUCKET_CAP) ? BUCKET_CAP : S.c;
        const int* users = padded + ((size_t)r << 5);
        int pidA = (c > 4) ? users[4 + q] : 0;       // group-1 pid

        // compute group 0
        float d = dot128(hl0, S.w0, S.w1) + dot128(hl1, S.w2, S.w3)
                + dot128(hl2, S.w4, S.w5) + dot128(hl3, S.w6, S.w7);
        d = red16(d);
        if (s == 0 && q < c) {
            float v = d + S.bv;
            out[S.pid0] = v > 0.0f ? v : 0.0f;
        }

        // issue next row's group-0 gathers (SN.pid0 has had time to land)
        const _Float16* irn = in_h + (size_t)(SN.pid0 >> 5) * HIDDEN + s * 8;
        half8 hn0 = *(const half8*)(irn);
        half8 hn1 = *(const half8*)(irn + 128);
        half8 hn2 = *(const half8*)(irn + 256);
        half8 hn3 = *(const half8*)(irn + 384);

        // remaining groups of row r (minority: P(c>4) ~ 0.48)
        for (int u = 4; u < c; u += 4) {
            const _Float16* ir = in_h + (size_t)(pidA >> 5) * HIDDEN + s * 8;
            const half8 a0 = *(const half8*)(ir);
            const half8 a1 = *(const half8*)(ir + 128);
            const half8 a2 = *(const half8*)(ir + 256);
            const half8 a3 = *(const half8*)(ir + 384);
            const int pidS = pidA;
            pidA = (u + 4 < c) ? users[u + 4 + q] : 0;   // idx <= 31, safe
            float e = dot128(a0, S.w0, S.w1) + dot128(a1, S.w2, S.w3)
                    + dot128(a2, S.w4, S.w5) + dot128(a3, S.w6, S.w7);
            e = red16(e);
            if (s == 0 && q < c - u) {
                float v = e + S.bv;
                out[pidS] = v > 0.0f ? v : 0.0f;
            }
        }

        if (r + 1 >= r_end) break;                   // last row done
        r = rn;
        S = SN;
        hl0 = hn0; hl1 = hn1; hl2 = hn2; hl3 = hn3;
    }
}

// ---------------------------------------------------------------------------
// Fallback (ws too small): round-1 fp32 token-centric, known-good 97us.
// ---------------------------------------------------------------------------
__global__ __launch_bounds__(256) void dynamic_ffn_f32_kernel(
    const float* __restrict__ input,
    const int*   __restrict__ mask,
    const float* __restrict__ weight,
    const float* __restrict__ bias,
    float*       __restrict__ out,
    int n_tokens)
{
    const int token = blockIdx.x;
    if (token >= n_tokens) return;
    const int wave = threadIdx.x >> 6;
    const int lane = threadIdx.x & 63;

    const float* in_row = input + (size_t)token * HIDDEN + lane * 8;
    const float4 x0 = *(const float4*)(in_row);
    const float4 x1 = *(const float4*)(in_row + 4);

    const int* midx = mask + (size_t)token * M_PER_TOKEN + wave * 8;
    float*     orow = out  + (size_t)token * M_PER_TOKEN + wave * 8;

    int idx[8];
#pragma unroll
    for (int j = 0; j < 8; ++j) idx[j] = midx[j];

    float acc[8];
#pragma unroll
    for (int j = 0; j < 8; ++j) {
        const float* w = weight + (size_t)idx[j] * HIDDEN + lane * 8;
        const float4 a = *(const float4*)(w);
        const float4 b = *(const float4*)(w + 4);
        acc[j] = x0.x * a.x + x0.y * a.y + x0.z * a.z + x0.w * a.w
               + x1.x * b.x + x1.y * b.y + x1.z * b.z + x1.w * b.w;
    }
#pragma unroll
    for (int j = 0; j < 8; ++j) {
        float p = acc[j];
#pragma unroll
        for (int off = 32; off > 0; off >>= 1)
            p += __shfl_down(p, off, 64);
        if (lane == 0) {
            float v = p + bias[idx[j]];
            orow[j] = v > 0.0f ? v : 0.0f;
        }
    }
}

extern "C" void kernel_launch(void* const* d_in, const int* in_sizes, int n_in,
                              void* d_out, int out_size, void* d_ws, size_t ws_size,
                              hipStream_t stream) {
    const float* input  = (const float*)d_in[0];   // [4,2048,512] fp32
    const int*   mask   = (const int*)  d_in[1];   // [4,2048,32] int32
    const float* weight = (const float*)d_in[2];   // [50000,512] fp32
    const float* bias   = (const float*)d_in[3];   // [50000] fp32
    float*       out    = (float*)d_out;           // [4,2048,32] fp32

    const int n_tokens = in_sizes[0] / HIDDEN;     // 8192
    const int n_pairs  = in_sizes[1];              // 262144
    const int n_rows   = in_sizes[2] / HIDDEN;     // 50000

    const size_t in_h_bytes   = (size_t)in_sizes[0] * sizeof(_Float16);    // 8.4MB
    const size_t counts_bytes = (size_t)n_rows * sizeof(int);              // 200KB
    const size_t padded_bytes = (size_t)n_rows * BUCKET_CAP * sizeof(int); // 6.4MB
    const size_t need = in_h_bytes + counts_bytes + padded_bytes;

    if (ws_size >= need) {
        _Float16* in_h   = (_Float16*)d_ws;
        int*      counts = (int*)((char*)d_ws + in_h_bytes);
        int*      padded = (int*)((char*)d_ws + in_h_bytes + counts_bytes);

        const int n_chunks = in_sizes[0] / 8;      // 524288
        prep_kernel<<<(n_chunks + 255) / 256, 256, 0, stream>>>(
            input, in_h, counts, padded, n_chunks, n_rows);

        const int sc_threads = (n_pairs + 3) / 4;  // 65536
        scatter_kernel<<<(sc_threads + 255) / 256, 256, 0, stream>>>(
            mask, counts, padded, n_pairs);

        const int n_wave_rows    = (n_rows + RPW - 1) / RPW;   // 6250
        const int n_blocks       = (n_wave_rows + 3) / 4;      // 1563
        const int blocks_per_xcd = (n_blocks + 7) / 8;         // 196
        const int grid           = blocks_per_xcd * 8;         // 1568
        row_ffn_kernel<<<grid, 256, 0, stream>>>(
            in_h, weight, bias, counts, padded, out, n_rows, blocks_per_xcd);
    } else {
        dynamic_ffn_f32_kernel<<<n_tokens, 256, 0, stream>>>(
            input, mask, weight, bias, out, n_tokens);
    }
}